// Round 2
// baseline (448.195 us; speedup 1.0000x reference)
//
#include <hip/hip_runtime.h>

// SKLinear: out = (h @ A_cat @ B_cat)/8 + bias,
//   A_cat (4096x1024) = [S1_l columns | U2_l columns], B_cat (1024x4096) = [U1_l rows ; S2_l rows]
// Pipeline: cvt h->bf16; pack A_cat^T,B_cat^T (bf16, N-major x K); GEMM1 -> T bf16; GEMM2 -> f32 out.

using bf16x8 = __attribute__((ext_vector_type(8))) __bf16;
using f32x4  = __attribute__((ext_vector_type(4))) float;

__device__ __forceinline__ unsigned short f2bf(float f) {
    union { float f; unsigned u; } c; c.f = f;
    unsigned u = c.u;
    return (unsigned short)((u + 0x7FFFu + ((u >> 16) & 1u)) >> 16);  // RNE
}

__device__ __forceinline__ void gload_lds16(const void* g, void* l) {
    __builtin_amdgcn_global_load_lds((const __attribute__((address_space(1))) void*)g,
                                     (__attribute__((address_space(3))) void*)l,
                                     16, 0, 0);
}

// ---------------- f32 -> bf16 elementwise (h_in) ----------------
__global__ void cvt_f32_to_bf16(const float4* __restrict__ src, ushort4* __restrict__ dst, int n4) {
    int i = blockIdx.x * blockDim.x + threadIdx.x;
    int stride = gridDim.x * blockDim.x;
    for (; i < n4; i += stride) {
        float4 v = src[i];
        ushort4 o;
        o.x = f2bf(v.x); o.y = f2bf(v.y); o.z = f2bf(v.z); o.w = f2bf(v.w);
        dst[i] = o;
    }
}

// ---------------- transpose-pack: dst[c*dstStride + r] = bf16(src[r*srcStride + c]) ----------------
// blockIdx.z = t in [0,8): src = (t<4 ? p0[t] : p1[t-4]); dst += t*dstTOff
__global__ void pack_transpose(const float* __restrict__ p0, const float* __restrict__ p1,
                               unsigned short* __restrict__ dst,
                               int srcStride, int dstStride, long perT, long dstTOff) {
    const int t = blockIdx.z;
    const float* src = (t < 4) ? (p0 + (long)t * perT) : (p1 + (long)(t - 4) * perT);
    unsigned short* d = dst + (long)t * dstTOff;
    const int r0 = blockIdx.x * 32, c0 = blockIdx.y * 32;
    __shared__ float tile[32][33];
    const int tx = threadIdx.x & 31, ty = threadIdx.x >> 5;
#pragma unroll
    for (int j = 0; j < 4; ++j) {
        int rr = ty + j * 8;
        tile[rr][tx] = src[(long)(r0 + rr) * srcStride + c0 + tx];
    }
    __syncthreads();
#pragma unroll
    for (int j = 0; j < 4; ++j) {
        int cc = ty + j * 8;
        d[(long)(c0 + cc) * dstStride + r0 + tx] = f2bf(tile[tx][cc]);
    }
}

// ---------------- GEMM: C(MxN) = A(MxK,row-major bf16) * Bt(NxK,row-major bf16)^T ----------------
// 128x128 tile, BK=32, 256 threads = 4 waves (2x2 of 64x64), mfma_f32_16x16x32_bf16.
template <bool OUT_BF16>
__global__ __launch_bounds__(256) void gemm_bt(const unsigned short* __restrict__ A,
                                               const unsigned short* __restrict__ Bt,
                                               void* __restrict__ Cout,
                                               const float* __restrict__ bias,
                                               int M, int N, int K, float scale) {
    __shared__ unsigned short lA[128 * 32];
    __shared__ unsigned short lB[128 * 32];
    const int tid = threadIdx.x;
    const int wave = tid >> 6, lane = tid & 63;
    const int m0 = blockIdx.y * 128, n0 = blockIdx.x * 128;
    const int wm = wave >> 1, wn = wave & 1;

    f32x4 acc[4][4] = {};

    // staging addresses: wave w covers rows [w*32, w*32+32) of the tile, 2 issues of 16 rows
    const unsigned short* gA = A + (size_t)(m0 + wave * 32 + (lane >> 2)) * K + (lane & 3) * 8;
    const unsigned short* gB = Bt + (size_t)(n0 + wave * 32 + (lane >> 2)) * K + (lane & 3) * 8;
    unsigned short* lA0 = &lA[(wave * 32) * 32];
    unsigned short* lB0 = &lB[(wave * 32) * 32];

    const unsigned short* pa = &lA[(wm * 64 + (lane & 15)) * 32 + (lane >> 4) * 8];
    const unsigned short* pb = &lB[(wn * 64 + (lane & 15)) * 32 + (lane >> 4) * 8];

    for (int kt = 0; kt < K; kt += 32) {
        gload_lds16(gA, lA0);
        gload_lds16(gA + (size_t)16 * K, lA0 + 16 * 32);
        gload_lds16(gB, lB0);
        gload_lds16(gB + (size_t)16 * K, lB0 + 16 * 32);
        __syncthreads();
        bf16x8 av[4], bv[4];
#pragma unroll
        for (int i = 0; i < 4; ++i) {
            av[i] = *(const bf16x8*)(pa + i * 16 * 32);
            bv[i] = *(const bf16x8*)(pb + i * 16 * 32);
        }
#pragma unroll
        for (int i = 0; i < 4; ++i)
#pragma unroll
            for (int j = 0; j < 4; ++j)
                acc[i][j] = __builtin_amdgcn_mfma_f32_16x16x32_bf16(av[i], bv[j], acc[i][j], 0, 0, 0);
        __syncthreads();
        gA += 32; gB += 32;
    }

    // epilogue: C/D layout col=lane&15, row=(lane>>4)*4+j
    const int row0 = m0 + wm * 64, col0 = n0 + wn * 64;
    const int lr = (lane >> 4) * 4, lc = lane & 15;
    if (OUT_BF16) {
        unsigned short* Cb = (unsigned short*)Cout;
#pragma unroll
        for (int i = 0; i < 4; ++i)
#pragma unroll
            for (int j = 0; j < 4; ++j) {
                int col = col0 + j * 16 + lc;
#pragma unroll
                for (int q = 0; q < 4; ++q) {
                    int row = row0 + i * 16 + lr + q;
                    Cb[(size_t)row * N + col] = f2bf(acc[i][j][q]);
                }
            }
    } else {
        float* Cf = (float*)Cout;
#pragma unroll
        for (int i = 0; i < 4; ++i)
#pragma unroll
            for (int j = 0; j < 4; ++j) {
                int col = col0 + j * 16 + lc;
                float bv = bias[col];
#pragma unroll
                for (int q = 0; q < 4; ++q) {
                    int row = row0 + i * 16 + lr + q;
                    Cf[(size_t)row * N + col] = acc[i][j][q] * scale + bv;
                }
            }
    }
}

extern "C" void kernel_launch(void* const* d_in, const int* in_sizes, int n_in,
                              void* d_out, int out_size, void* d_ws, size_t ws_size,
                              hipStream_t stream) {
    const float* h_in = (const float*)d_in[0];  // (8192, 4096)
    const float* S1s  = (const float*)d_in[1];  // (4, 4096, 128)
    const float* S2s  = (const float*)d_in[2];  // (4, 128, 4096)
    const float* U1s  = (const float*)d_in[3];  // (4, 128, 4096)
    const float* U2s  = (const float*)d_in[4];  // (4, 4096, 128)
    const float* bias = (const float*)d_in[5];  // (4096,)
    float* out = (float*)d_out;                 // (8192, 4096) f32

    constexpr int B = 8192, IN = 4096, OUTD = 4096, R = 128;
    constexpr int NC = 1024;  // 2*L*R

    char* ws = (char*)d_ws;
    unsigned short* hB    = (unsigned short*)ws;                        // 64 MiB: h bf16 (B x IN)
    unsigned short* AcatT = (unsigned short*)(ws + ((size_t)64 << 20)); //  8 MiB: A_cat^T (NC x IN)
    unsigned short* BcatT = (unsigned short*)(ws + ((size_t)72 << 20)); //  8 MiB: B_cat^T (OUT x NC)
    unsigned short* T     = (unsigned short*)(ws + ((size_t)80 << 20)); // 16 MiB: T bf16 (B x NC)

    cvt_f32_to_bf16<<<2048, 256, 0, stream>>>((const float4*)h_in, (ushort4*)hB, B * IN / 4);

    // A_cat^T[n= t*128+r][i] = (t<4 ? S1s[t][i][r] : U2s[t-4][i][r])
    pack_transpose<<<dim3(IN / 32, R / 32, 8), 256, 0, stream>>>(
        S1s, U2s, AcatT, R, IN, (long)IN * R, (long)R * IN);
    // B_cat^T[o][n= t*128+r] = (t<4 ? U1s[t][r][o] : S2s[t-4][r][o])
    pack_transpose<<<dim3(R / 32, OUTD / 32, 8), 256, 0, stream>>>(
        U1s, S2s, BcatT, OUTD, NC, (long)R * OUTD, (long)R);

    // GEMM1: T(B x NC) = hB (B x IN) * AcatT^T
    gemm_bt<true><<<dim3(NC / 128, B / 128), 256, 0, stream>>>(hB, AcatT, (void*)T, nullptr,
                                                               B, NC, IN, 1.0f);
    // GEMM2: out(B x OUT) = T (B x NC) * BcatT^T, scaled 1/8 + bias
    gemm_bt<false><<<dim3(OUTD / 128, B / 128), 256, 0, stream>>>(T, BcatT, (void*)out, bias,
                                                                  B, OUTD, NC, 0.125f);
}

// Round 3
// 402.849 us; speedup vs baseline: 1.1126x; 1.1126x over previous
//
#include <hip/hip_runtime.h>

// SKLinear: out = (h @ A_cat @ B_cat)/8 + bias
//   A_cat (4096x1024) = [S1_l cols | U2_l cols], B_cat (1024x4096) = [U1_l rows ; S2_l rows]
// Pipeline: cvt h->bf16; pack A_cat^T,B_cat^T (N-major x K, bf16); 8-phase MFMA GEMM1 -> T bf16;
//           8-phase MFMA GEMM2 (-> f32 out, NT stores, /8 + bias).

using bf16x8 = __attribute__((ext_vector_type(8))) __bf16;
using f32x4  = __attribute__((ext_vector_type(4))) float;

__device__ __forceinline__ unsigned short f2bf(float f) {
    union { float f; unsigned u; } c; c.f = f;
    unsigned u = c.u;
    return (unsigned short)((u + 0x7FFFu + ((u >> 16) & 1u)) >> 16);  // RNE
}

__device__ __forceinline__ void gload_lds16(const void* g, void* l) {
    __builtin_amdgcn_global_load_lds((const __attribute__((address_space(1))) void*)g,
                                     (__attribute__((address_space(3))) void*)l,
                                     16, 0, 0);
}

// ---------------- f32 -> bf16 elementwise (h_in) ----------------
__global__ void cvt_f32_to_bf16(const float4* __restrict__ src, ushort4* __restrict__ dst, int n4) {
    int i = blockIdx.x * blockDim.x + threadIdx.x;
    int stride = gridDim.x * blockDim.x;
    for (; i < n4; i += stride) {
        float4 v = src[i];
        ushort4 o;
        o.x = f2bf(v.x); o.y = f2bf(v.y); o.z = f2bf(v.z); o.w = f2bf(v.w);
        dst[i] = o;
    }
}

// ---------------- transpose-pack: dst[c*dstStride + r] = bf16(src[r*srcStride + c]) ----------------
__global__ void pack_transpose(const float* __restrict__ p0, const float* __restrict__ p1,
                               unsigned short* __restrict__ dst,
                               int srcStride, int dstStride, long perT, long dstTOff) {
    const int t = blockIdx.z;
    const float* src = (t < 4) ? (p0 + (long)t * perT) : (p1 + (long)(t - 4) * perT);
    unsigned short* d = dst + (long)t * dstTOff;
    const int r0 = blockIdx.x * 32, c0 = blockIdx.y * 32;
    __shared__ float tile[32][33];
    const int tx = threadIdx.x & 31, ty = threadIdx.x >> 5;
#pragma unroll
    for (int j = 0; j < 4; ++j) {
        int rr = ty + j * 8;
        tile[rr][tx] = src[(long)(r0 + rr) * srcStride + c0 + tx];
    }
    __syncthreads();
#pragma unroll
    for (int j = 0; j < 4; ++j) {
        int cc = ty + j * 8;
        d[(long)(c0 + cc) * dstStride + r0 + tx] = f2bf(tile[tx][cc]);
    }
}

// ---------------- 8-phase 256xBN GEMM: C(MxN) = A(MxK) * Bt(NxK)^T, bf16 in, f32 acc -------------
// BM=256, BK=64, 512 threads = 8 waves (2M x 4N). Per-wave out 128 x (BN/4).
// LDS: dbuf x [A 256x64 (2 halves of 128x64) + B BNx64 (2 halves)], XOR-swizzled (chunk ^= row&7).
// Schedule per K-tile t (buf c=t&1): P1{ldsA0-3+ldsB-lo | stage B0(t+1)->!c | bar | lgkm0 | MFMA}
//   P2{ldsA4-7+ldsB-hi | stage B1(t+1)} P3{stage A0(t+2)->c | MFMA} P4{stage A1(t+2) | MFMA}.
// vmcnt(4) once per tile start (A(t+1) halves = 4 loads in flight); vmcnt(0) at peeled last tile.

#define SB() __builtin_amdgcn_s_barrier()
#define WVM(n) { asm volatile("s_waitcnt vmcnt(" #n ")" ::: "memory"); __builtin_amdgcn_sched_barrier(0); }
#define WLG() { asm volatile("s_waitcnt lgkmcnt(0)" ::: "memory"); __builtin_amdgcn_sched_barrier(0); }

template <int BN, bool OUT_BF16>
__global__ __launch_bounds__(512, 2) void gemm8p(const unsigned short* __restrict__ A,
                                                 const unsigned short* __restrict__ Bt,
                                                 void* __restrict__ Cout,
                                                 const float* __restrict__ bias,
                                                 int M, int N, int K, float scale) {
    constexpr int BM = 256;
    constexpr int NF = BN / 64;            // N-frags per wave (4 or 2)
    constexpr int WN = BN / 4;             // wave N extent (64 or 32)
    constexpr int BHALF = BN * 64;         // bytes per B half-tile
    constexpr int BUFB = 32768 + BN * 128; // bytes per K-tile buffer
    __shared__ __align__(128) char smem[2 * BUFB];

    const int tid = threadIdx.x;
    const int w = tid >> 6, lane = tid & 63;
    const int wm = w >> 2, wn = w & 3;

    // XCD-aware swizzle (nwg % 8 == 0 for both instantiations)
    const int nwg = gridDim.x;
    const int wg = blockIdx.x;
    const int swz = (wg & 7) * (nwg >> 3) + (wg >> 3);
    const int nbn = N / BN;
    const int m0 = (swz / nbn) * BM, n0 = (swz % nbn) * BN;

    const int NT = K >> 6;

    // staging lane constants: row-in-8 rl, swizzled 16B-chunk csw = chunk ^ (row&7)
    const int rl = lane >> 3;
    const int csw = (lane & 7) ^ rl;
    const unsigned short* gA = A + (size_t)(m0 + w * 8 + rl) * K + csw * 8;
    const unsigned short* gB = Bt + (size_t)(n0 + w * 8 + rl) * K + csw * 8;

    // ds_read lane constants: row&7 == lane&7 for all frags -> shared swizzled chunk offsets
    const int aRB = wm * 16384 + (lane & 15) * 128;
    const int bRB = 32768 + (wn >> 1) * BHALF + ((wn & 1) * WN + (lane & 15)) * 128;
    const int ch0 = (((lane >> 4) + 0) ^ (lane & 7)) << 4;
    const int ch1 = (((lane >> 4) + 4) ^ (lane & 7)) << 4;

    f32x4 acc[8][NF] = {};
    bf16x8 av[8][2], bv[NF][2];

#define STAGE_A(tt, h) {                                                              \
        const unsigned short* g_ = gA + (size_t)((h) * 128) * K + (size_t)(tt) * 64;  \
        char* l_ = smem + ((tt) & 1) * BUFB + (h) * 16384 + w * 1024;                 \
        gload_lds16(g_, l_);                                                          \
        gload_lds16(g_ + (size_t)64 * K, l_ + 8192); }

#define STAGE_B(tt, h) {                                                                   \
        const unsigned short* g_ = gB + (size_t)((h) * (BN / 2)) * K + (size_t)(tt) * 64;  \
        char* l_ = smem + ((tt) & 1) * BUFB + 32768 + (h) * BHALF + w * 1024;              \
        gload_lds16(g_, l_);                                                               \
        if (BN == 256) gload_lds16(g_ + (size_t)64 * K, l_ + 8192); }

#define LOADA(c, base) {                                                            \
        _Pragma("unroll")                                                           \
        for (int f_ = 0; f_ < 4; ++f_) {                                            \
            const char* p_ = smem + (c) * BUFB + aRB + ((base) + f_) * 2048;        \
            av[(base) + f_][0] = *(const bf16x8*)(p_ + ch0);                        \
            av[(base) + f_][1] = *(const bf16x8*)(p_ + ch1);                        \
        } }

#define LOADB(c, base) {                                                            \
        _Pragma("unroll")                                                           \
        for (int f_ = 0; f_ < NF / 2; ++f_) {                                       \
            const char* p_ = smem + (c) * BUFB + bRB + ((base) + f_) * 2048;        \
            bv[(base) + f_][0] = *(const bf16x8*)(p_ + ch0);                        \
            bv[(base) + f_][1] = *(const bf16x8*)(p_ + ch1);                        \
        } }

#define BURST(mb, nb) {                                                             \
        __builtin_amdgcn_s_setprio(1);                                              \
        _Pragma("unroll")                                                           \
        for (int f_ = 0; f_ < 4; ++f_)                                              \
            _Pragma("unroll")                                                       \
            for (int g_ = 0; g_ < NF / 2; ++g_) {                                   \
                acc[(mb) + f_][(nb) + g_] = __builtin_amdgcn_mfma_f32_16x16x32_bf16(\
                    av[(mb) + f_][0], bv[(nb) + g_][0], acc[(mb) + f_][(nb) + g_], 0, 0, 0); \
                acc[(mb) + f_][(nb) + g_] = __builtin_amdgcn_mfma_f32_16x16x32_bf16(\
                    av[(mb) + f_][1], bv[(nb) + g_][1], acc[(mb) + f_][(nb) + g_], 0, 0, 0); \
            }                                                                       \
        __builtin_amdgcn_s_setprio(0); }

    // prologue: tile0 (A,B) -> buf0, tile1 A -> buf1  (10 or 12 loads; vmcnt(4) leaves A(1))
    STAGE_A(0, 0); STAGE_A(0, 1);
    STAGE_B(0, 0); STAGE_B(0, 1);
    STAGE_A(1, 0); STAGE_A(1, 1);

    for (int t = 0; t < NT - 1; ++t) {
        const int c = t & 1;
        WVM(4); SB();
        // P1
        LOADA(c, 0); LOADB(c, 0);
        STAGE_B(t + 1, 0);
        SB(); WLG();
        BURST(0, 0);
        SB();
        // P2
        LOADA(c, 4); LOADB(c, NF / 2);
        STAGE_B(t + 1, 1);
        SB(); WLG();
        BURST(4, 0);
        SB();
        // P3
        if (t + 2 < NT) STAGE_A(t + 2, 0);
        SB();
        BURST(0, NF / 2);
        SB();
        // P4
        if (t + 2 < NT) STAGE_A(t + 2, 1);
        SB();
        BURST(4, NF / 2);
    }
    {   // peeled last tile: everything must have landed
        const int c = (NT - 1) & 1;
        WVM(0); SB();
        LOADA(c, 0); LOADB(c, 0);
        SB(); WLG();
        BURST(0, 0); SB();
        LOADA(c, 4); LOADB(c, NF / 2);
        SB(); WLG();
        BURST(4, 0); SB();
        BURST(0, NF / 2); SB();
        BURST(4, NF / 2);
    }

    // epilogue: D layout col=lane&15, row=(lane>>4)*4+q
    const int lc = lane & 15, lr = (lane >> 4) * 4;
#pragma unroll
    for (int fm = 0; fm < 8; ++fm)
#pragma unroll
        for (int fn = 0; fn < NF; ++fn) {
            const int col = n0 + wn * WN + fn * 16 + lc;
            const int row = m0 + wm * 128 + fm * 16 + lr;
            if constexpr (OUT_BF16) {
                unsigned short* Cb = (unsigned short*)Cout;
#pragma unroll
                for (int q = 0; q < 4; ++q)
                    Cb[(size_t)(row + q) * N + col] = f2bf(acc[fm][fn][q]);
            } else {
                float* Cf = (float*)Cout;
                const float bb = bias[col];
#pragma unroll
                for (int q = 0; q < 4; ++q)
                    __builtin_nontemporal_store(acc[fm][fn][q] * scale + bb,
                                                &Cf[(size_t)(row + q) * N + col]);
            }
        }
#undef STAGE_A
#undef STAGE_B
#undef LOADA
#undef LOADB
#undef BURST
}

extern "C" void kernel_launch(void* const* d_in, const int* in_sizes, int n_in,
                              void* d_out, int out_size, void* d_ws, size_t ws_size,
                              hipStream_t stream) {
    const float* h_in = (const float*)d_in[0];  // (8192, 4096)
    const float* S1s  = (const float*)d_in[1];  // (4, 4096, 128)
    const float* S2s  = (const float*)d_in[2];  // (4, 128, 4096)
    const float* U1s  = (const float*)d_in[3];  // (4, 128, 4096)
    const float* U2s  = (const float*)d_in[4];  // (4, 4096, 128)
    const float* bias = (const float*)d_in[5];  // (4096,)
    float* out = (float*)d_out;                 // (8192, 4096) f32

    constexpr int B = 8192, IN = 4096, OUTD = 4096, R = 128;
    constexpr int NC = 1024;  // 2*L*R

    char* ws = (char*)d_ws;
    unsigned short* hB    = (unsigned short*)ws;                        // 64 MiB: h bf16 (B x IN)
    unsigned short* AcatT = (unsigned short*)(ws + ((size_t)64 << 20)); //  8 MiB: A_cat^T (NC x IN)
    unsigned short* BcatT = (unsigned short*)(ws + ((size_t)72 << 20)); //  8 MiB: B_cat^T (OUT x NC)
    unsigned short* T     = (unsigned short*)(ws + ((size_t)80 << 20)); // 16 MiB: T bf16 (B x NC)

    cvt_f32_to_bf16<<<2048, 256, 0, stream>>>((const float4*)h_in, (ushort4*)hB, B * IN / 4);

    // A_cat^T[n = t*128+r][i] = (t<4 ? S1s[t][i][r] : U2s[t-4][i][r])
    pack_transpose<<<dim3(IN / 32, R / 32, 8), 256, 0, stream>>>(
        S1s, U2s, AcatT, R, IN, (long)IN * R, (long)R * IN);
    // B_cat^T[o][n = t*128+r] = (t<4 ? U1s[t][r][o] : S2s[t-4][r][o])
    pack_transpose<<<dim3(R / 32, OUTD / 32, 8), 256, 0, stream>>>(
        U1s, S2s, BcatT, OUTD, NC, (long)R * OUTD, (long)R);

    // GEMM1: T(B x NC) = hB * AcatT^T      — 256x128 tiles -> 32*8 = 256 blocks (1/CU)
    gemm8p<128, true><<<dim3((B / 256) * (NC / 128)), 512, 0, stream>>>(
        hB, AcatT, (void*)T, nullptr, B, NC, IN, 1.0f);
    // GEMM2: out(B x OUT) = T * BcatT^T, /8 + bias — 256x256 tiles -> 32*16 = 512 blocks
    gemm8p<256, false><<<dim3((B / 256) * (OUTD / 256)), 512, 0, stream>>>(
        T, BcatT, (void*)out, bias, B, OUTD, NC, 0.125f);
}